// Round 1
// baseline (348.009 us; speedup 1.0000x reference)
//
#include <hip/hip_runtime.h>

// SuperONN1d = implicit GEMM.
//   Stage 1 (xq_prep): shift-lerp + powers -> XQ_T[b][lp][qc] bf16, lp = l+4
//     (guard rows absorb conv padding). v2: coalesced x staging into odd-stride
//     LDS tile (lanes along l), then compute with lanes along ci (w1/floor(sh)
//     hoisted per ci; v0(ll+1)=v1(ll) chain). 32 l-rows per block.
//   Stage 2 (prep_weights): A[co][k] -> per-chunk swizzled fragments so an
//     identity DMA copy produces a XOR-swizzled LDS tile (conflict-free reads).
//   Stage 3 (gemm): 1024 blocks x 256 thr (4 waves), 128co x 128l tile, BK=64.
//     v2: loop nest inverted to s-outer / tap-inner with the 136x64 B column
//     slice RESIDENT in LDS across all 9 taps (tap re-reads were 9x XQ traffic,
//     438 MB HBM fetch). Per chunk only the 16 KB L2-hot A tile is DMA'd, so
//     the per-chunk barrier drains ~L2 latency, not HBM. 33.8 KB LDS -> 4
//     blocks/CU for cross-block overlap of the barrier drains.

#define B_    16
#define CIN   128
#define L_    8192
#define COUT  128
#define K_    9
#define QMAX  3
#define KQ    (QMAX * CIN)        // 384
#define KTOT  (K_ * KQ)           // 3456
#define BK    64
#define GUARD 4
#define LROWS (L_ + 2 * GUARD)    // 8200
#define XQOFF (1u << 20)          // XQ at d_ws + 1 MB (A fragments first)

typedef __attribute__((ext_vector_type(8)))  short bf16x8;
typedef __attribute__((ext_vector_type(16))) float f32x16;
typedef __attribute__((ext_vector_type(4)))  int   int4v;

__device__ __forceinline__ unsigned short f2bf(float v) {
    union { float f; unsigned u; } cv; cv.f = v;
    unsigned u = cv.u;
    return (unsigned short)((u + 0x7FFFu + ((u >> 16) & 1u)) >> 16);  // RNE
}

// ---- A prep: w[co][qc][tap] -> wa[c][co][slot s8][i], swizzled:
//   LDS 16B-slot (co, s8) must hold elements k = c*64 + (s8 ^ (co&7))*8 + i
__global__ __launch_bounds__(256) void prep_weights(
    const float* __restrict__ w, unsigned short* __restrict__ wa)
{
    int g = blockIdx.x * 256 + threadIdx.x;
    if (g >= COUT * KTOT) return;
    const int c   = g >> 13;             // chunk (8192 shorts each)
    const int r   = g & 8191;
    const int co  = r >> 6;              // row = 64 shorts = 128 B
    const int s8  = (r >> 3) & 7;
    const int i   = r & 7;
    const int kk  = ((s8 ^ (co & 7)) << 3) | i;
    const int k   = c * BK + kk;
    const int tap = k / KQ;
    const int qc  = k - tap * KQ;
    wa[g] = f2bf(w[((size_t)co * KQ + qc) * K_ + tap]);
}

// ---- XQ prep v2: coalesced stage -> LDS compute -> contiguous copy-out ----
//   block covers 32 l-rows x 128 ci. LDS: xtile 128x65 f32 (33.3 KB, odd
//   stride = conflict-free both lane-along-l writes and lane-along-ci reads)
//   + out tile 32x384 bf16 (24 KB). 57.8 KB -> 2 blocks/CU.
__global__ __launch_bounds__(256) void xq_prep(
    const float* __restrict__ x, const float* __restrict__ shifts,
    unsigned short* __restrict__ xq)
{
    __shared__ float xtile[128 * 65];            // 33,280 B
    __shared__ unsigned short tile[32 * KQ];     // 24,576 B
    const int l0   = blockIdx.x * 32;
    const int b    = blockIdx.y;
    const int tid  = threadIdx.x;
    const int lane = tid & 63;
    const int w    = tid >> 6;
    const float* xb = x + (size_t)b * CIN * L_;

    // stage: row r, cols l0-4 .. l0+59 (covers all i0 in [l0-2, l0+34+1])
    const int col = l0 - 4 + lane;
    const bool cok = (col >= 0) & (col < L_);
#pragma unroll 4
    for (int r = w; r < 128; r += 4)
        xtile[r * 65 + lane] = cok ? xb[(size_t)r * L_ + col] : 0.0f;
    __syncthreads();

    // compute: lanes along ci; w1 and floor(shift) constant per ci
    {
        const int ci   = tid & 127;
        const int lgrp = tid >> 7;               // 0..1, 16 ll each
        const float sh = shifts[2 * ci] * 4.0f;  // MAX_SHIFT
        const float fl = floorf(sh);
        const int  ifl = (int)fl;
        const float w1 = sh - fl;
        // xtile col for v0 at ll: c0 = ll + 4 + ifl  (range [2,36])
        int c0 = lgrp * 16 + 4 + ifl;
        float v_prev = xtile[ci * 65 + c0];
#pragma unroll
        for (int j = 0; j < 16; ++j) {
            const int ll = lgrp * 16 + j;
            const float v_next = xtile[ci * 65 + c0 + 1];
            const float xs = fmaf(w1, v_next - v_prev, v_prev);
            const float x2 = xs * xs;
            const float x3 = x2 * xs;
            tile[ll * KQ + ci]       = f2bf(xs);
            tile[ll * KQ + 128 + ci] = f2bf(x2);
            tile[ll * KQ + 256 + ci] = f2bf(x3);
            v_prev = v_next;
            ++c0;
        }
    }
    __syncthreads();

    // contiguous 24 KB copy out (rows lp = l0+4 .. l0+35)
    const int4v* src = (const int4v*)tile;
    int4v* dst = (int4v*)(xq + ((size_t)b * LROWS + l0 + GUARD) * KQ);
#pragma unroll
    for (int it = 0; it < 6; ++it)
        dst[it * 256 + tid] = src[it * 256 + tid];

    if (blockIdx.x == 0) {          // zero guard rows lp 0..3
        int4v* g0 = (int4v*)(xq + (size_t)b * LROWS * KQ);
        if (tid < 192) g0[tid] = (int4v){0, 0, 0, 0};
    }
    if (blockIdx.x == gridDim.x - 1) {  // zero guard rows lp 8196..8199
        int4v* g1 = (int4v*)(xq + ((size_t)b * LROWS + L_ + GUARD) * KQ);
        if (tid < 192) g1[tid] = (int4v){0, 0, 0, 0};
    }
}

// ---- GEMM v2: s-outer / tap-inner, B column-slice resident in LDS ----
__global__ __launch_bounds__(256, 4) void gemm(
    const unsigned short* __restrict__ wa,   // [54][128][64] swizzled bf16
    const unsigned short* __restrict__ xq,   // [B_][LROWS][KQ] bf16
    const float*          __restrict__ bias,
    float*                __restrict__ out)
{
    __shared__ __align__(16) unsigned short ldsA[COUT * BK];  // 16 KB
    __shared__ __align__(16) unsigned short ldsB[136 * BK];   // 17,408 B

    const int l0   = blockIdx.x * 128;
    const int b    = blockIdx.y;
    const int tid  = threadIdx.x;
    const int lane = tid & 63;
    const int w    = tid >> 6;               // 0..3
    const int cobase = (w >> 1) * 64;
    const int nbase  = (w & 1) * 64;
    const int n5 = lane & 31;
    const int h  = lane >> 5;

    // B DMA lane pattern: lane j -> row (j>>3), slot (j&7)^((j>>3)&7)
    const int bj_row = lane >> 3;
    const size_t bLaneOff = (size_t)bj_row * KQ + (size_t)(((lane & 7) ^ (bj_row & 7)) << 3);

    // loop-invariant A fragment LDS byte addresses (XOR-swizzled)
    int aaddr[2][4];
#pragma unroll
    for (int fi = 0; fi < 2; ++fi)
#pragma unroll
        for (int kc = 0; kc < 4; ++kc) {
            const int ar = cobase + fi * 32 + n5;
            aaddr[fi][kc] = ar * 128 + ((((kc << 1) | h) ^ (ar & 7)) << 4);
        }

    f32x16 acc[2][2];
#pragma unroll
    for (int i = 0; i < 2; ++i)
#pragma unroll
        for (int j = 0; j < 2; ++j) acc[i][j] = (f32x16){};

    const unsigned short* xqb   = xq + (size_t)b * LROWS * KQ;
    const unsigned short* bbase = xqb + (size_t)l0 * KQ + bLaneOff;

#pragma unroll 1
    for (int s = 0; s < 6; ++s) {
        // stage B column slice: rows l0..l0+135, cols s*64..s*64+63 (17 groups)
        const unsigned short* bsrc = bbase + s * 64;
#pragma unroll
        for (int i = 0; i < 4; ++i) {
            const int g = w * 4 + i;
            __builtin_amdgcn_global_load_lds(
                (const __attribute__((address_space(1))) void*)(bsrc + (size_t)g * 8 * KQ),
                (__attribute__((address_space(3))) void*)((char*)ldsB + g * 1024),
                16, 0, 0);
        }
        if (w == 0)
            __builtin_amdgcn_global_load_lds(
                (const __attribute__((address_space(1))) void*)(bsrc + (size_t)16 * 8 * KQ),
                (__attribute__((address_space(3))) void*)((char*)ldsB + 16 * 1024),
                16, 0, 0);

#pragma unroll 1
        for (int tap = 0; tap < K_; ++tap) {
            const int c = tap * 6 + s;
            const unsigned short* agsrc = wa + (size_t)c * 8192 + (size_t)(w * 4) * 512 + lane * 8;
#pragma unroll
            for (int i = 0; i < 4; ++i)
                __builtin_amdgcn_global_load_lds(
                    (const __attribute__((address_space(1))) void*)(agsrc + i * 512),
                    (__attribute__((address_space(3))) void*)((char*)ldsA + (w * 4 + i) * 1024),
                    16, 0, 0);
            __syncthreads();   // drains vmcnt(0): A chunk (+B at tap 0) resident
#pragma unroll
            for (int kc = 0; kc < 4; ++kc) {
                const int br0 = tap + nbase + n5;
                const int ba0 = br0 * 128 + ((((kc << 1) | h) ^ (br0 & 7)) << 4);
                const int ba1 = ba0 + 32 * 128;   // (br0+32)&7 == br0&7
                const bf16x8 a0 = *(const bf16x8*)((const char*)ldsA + aaddr[0][kc]);
                const bf16x8 a1 = *(const bf16x8*)((const char*)ldsA + aaddr[1][kc]);
                const bf16x8 b0 = *(const bf16x8*)((const char*)ldsB + ba0);
                const bf16x8 b1 = *(const bf16x8*)((const char*)ldsB + ba1);
                acc[0][0] = __builtin_amdgcn_mfma_f32_32x32x16_bf16(a0, b0, acc[0][0], 0, 0, 0);
                acc[0][1] = __builtin_amdgcn_mfma_f32_32x32x16_bf16(a0, b1, acc[0][1], 0, 0, 0);
                acc[1][0] = __builtin_amdgcn_mfma_f32_32x32x16_bf16(a1, b0, acc[1][0], 0, 0, 0);
                acc[1][1] = __builtin_amdgcn_mfma_f32_32x32x16_bf16(a1, b1, acc[1][1], 0, 0, 0);
            }
            __syncthreads();   // all reads done before next chunk's DMA overwrites
        }
    }

    // ---- epilogue: + bias, coalesced stores ----
#pragma unroll
    for (int fi = 0; fi < 2; ++fi)
#pragma unroll
        for (int bj = 0; bj < 2; ++bj)
#pragma unroll
            for (int r = 0; r < 16; ++r) {
                const int co = cobase + fi * 32 + (r & 3) + 8 * (r >> 2) + 4 * h;
                const int l  = l0 + nbase + bj * 32 + n5;
                out[((size_t)(b * COUT + co)) * L_ + l] = acc[fi][bj][r] + bias[co];
            }
}

extern "C" void kernel_launch(void* const* d_in, const int* in_sizes, int n_in,
                              void* d_out, int out_size, void* d_ws, size_t ws_size,
                              hipStream_t stream) {
    const float* x      = (const float*)d_in[0];  // 16*128*8192
    const float* w      = (const float*)d_in[1];  // 128*384*9
    const float* bias   = (const float*)d_in[2];  // 128
    const float* shifts = (const float*)d_in[3];  // 128*2
    float* out = (float*)d_out;

    const size_t need = (size_t)XQOFF + (size_t)B_ * LROWS * KQ * 2;  // ~101.8 MB
    if (ws_size < need) return;   // clean fail instead of OOB corruption

    unsigned short* wa = (unsigned short*)d_ws;                       // 884,736 B
    unsigned short* xq = (unsigned short*)((char*)d_ws + XQOFF);      // 100.76 MB

    const int nw = COUT * KTOT;                                       // 442,368
    prep_weights<<<(nw + 255) / 256, 256, 0, stream>>>(w, wa);

    dim3 gq(L_ / 32, B_);                                             // 256 x 16
    xq_prep<<<gq, 256, 0, stream>>>(x, shifts, xq);

    dim3 gg(L_ / 128, B_);                                            // 64 x 16 = 1024
    gemm<<<gg, 256, 0, stream>>>(wa, xq, bias, out);
}

// Round 2
// 257.939 us; speedup vs baseline: 1.3492x; 1.3492x over previous
//
#include <hip/hip_runtime.h>

// SuperONN1d = implicit GEMM.
//   Stage 1 (xq_prep): shift-lerp + powers -> XQ_T[b][lp][qc] bf16, lp = l+4
//     (guard rows absorb conv padding). v3: coalesced x staging with ALL 32
//     per-thread loads register-staged before any LDS write (v2 had only ~4
//     loads in flight -> latency-bound at 1.3 TB/s, 150 us). Then transpose
//     compute with lanes along ci (w1/floor(sh) hoisted; v0(ll+1)=v1(ll)).
//   Stage 2 (prep_weights): A[co][k] -> per-chunk swizzled fragments so an
//     identity DMA copy produces a XOR-swizzled LDS tile (conflict-free reads).
//   Stage 3 (gemm): 1024 blocks x 256 thr (4 waves), 128co x 128l tile, BK=64.
//     s-outer / tap-inner with the 136x64 B column slice RESIDENT in LDS
//     across all 9 taps (kills the 9x XQ re-fetch). Per chunk only the 16 KB
//     L2-hot A tile is DMA'd. 33.8 KB LDS -> 4 blocks/CU for cross-block
//     overlap of the per-chunk barrier drains.

#define B_    16
#define CIN   128
#define L_    8192
#define COUT  128
#define K_    9
#define QMAX  3
#define KQ    (QMAX * CIN)        // 384
#define KTOT  (K_ * KQ)           // 3456
#define BK    64
#define GUARD 4
#define LROWS (L_ + 2 * GUARD)    // 8200
#define XQOFF (1u << 20)          // XQ at d_ws + 1 MB (A fragments first)

typedef __attribute__((ext_vector_type(8)))  short bf16x8;
typedef __attribute__((ext_vector_type(16))) float f32x16;
typedef __attribute__((ext_vector_type(4)))  int   int4v;

__device__ __forceinline__ unsigned short f2bf(float v) {
    union { float f; unsigned u; } cv; cv.f = v;
    unsigned u = cv.u;
    return (unsigned short)((u + 0x7FFFu + ((u >> 16) & 1u)) >> 16);  // RNE
}

// ---- A prep: w[co][qc][tap] -> wa[c][co][slot s8][i], swizzled:
//   LDS 16B-slot (co, s8) must hold elements k = c*64 + (s8 ^ (co&7))*8 + i
__global__ __launch_bounds__(256) void prep_weights(
    const float* __restrict__ w, unsigned short* __restrict__ wa)
{
    int g = blockIdx.x * 256 + threadIdx.x;
    if (g >= COUT * KTOT) return;
    const int c   = g >> 13;             // chunk (8192 shorts each)
    const int r   = g & 8191;
    const int co  = r >> 6;              // row = 64 shorts = 128 B
    const int s8  = (r >> 3) & 7;
    const int i   = r & 7;
    const int kk  = ((s8 ^ (co & 7)) << 3) | i;
    const int k   = c * BK + kk;
    const int tap = k / KQ;
    const int qc  = k - tap * KQ;
    wa[g] = f2bf(w[((size_t)co * KQ + qc) * K_ + tap]);
}

// ---- XQ prep v3: register-staged coalesced loads -> LDS transpose ----
//   block covers 32 l-rows x 128 ci. LDS: xtile 128x65 f32 (33.3 KB, odd
//   stride = conflict-free both lane-along-l writes and lane-along-ci reads)
//   + out tile 32x384 bf16 (24 KB). 57.8 KB -> 2 blocks/CU. 32 global loads
//   per thread issued back-to-back (register-staged) = ~64 KB in flight per
//   CU, hiding HBM latency that v2's load->ds_write interleave exposed.
__global__ __launch_bounds__(256) void xq_prep(
    const float* __restrict__ x, const float* __restrict__ shifts,
    unsigned short* __restrict__ xq)
{
    __shared__ float xtile[128 * 65];            // 33,280 B
    __shared__ unsigned short tile[32 * KQ];     // 24,576 B
    const int l0   = blockIdx.x * 32;
    const int b    = blockIdx.y;
    const int tid  = threadIdx.x;
    const int lane = tid & 63;
    const int w    = tid >> 6;
    const float* xb = x + (size_t)b * CIN * L_;

    // stage: row r (r == w mod 4), cols l0-4 .. l0+59
    const int col = l0 - 4 + lane;
    const bool cok = (col >= 0) & (col < L_);
    const float* xsrc = xb + col;
    float rv[32];
#pragma unroll
    for (int j = 0; j < 32; ++j)
        rv[j] = cok ? xsrc[(size_t)(j * 4 + w) * L_] : 0.0f;
#pragma unroll
    for (int j = 0; j < 32; ++j)
        xtile[(j * 4 + w) * 65 + lane] = rv[j];
    __syncthreads();

    // compute: lanes along ci; w1 and floor(shift) constant per ci
    {
        const int ci   = tid & 127;
        const int lgrp = tid >> 7;               // 0..1, 16 ll each
        const float sh = shifts[2 * ci] * 4.0f;  // MAX_SHIFT
        const float fl = floorf(sh);
        const int  ifl = (int)fl;
        const float w1 = sh - fl;
        // xtile col for v0 at ll: c0 = ll + 4 + ifl  (range [2,37])
        int c0 = lgrp * 16 + 4 + ifl;
        float v_prev = xtile[ci * 65 + c0];
#pragma unroll
        for (int j = 0; j < 16; ++j) {
            const int ll = lgrp * 16 + j;
            const float v_next = xtile[ci * 65 + c0 + 1];
            const float xs = fmaf(w1, v_next - v_prev, v_prev);
            const float x2 = xs * xs;
            const float x3 = x2 * xs;
            tile[ll * KQ + ci]       = f2bf(xs);
            tile[ll * KQ + 128 + ci] = f2bf(x2);
            tile[ll * KQ + 256 + ci] = f2bf(x3);
            v_prev = v_next;
            ++c0;
        }
    }
    __syncthreads();

    // contiguous 24 KB copy out (rows lp = l0+4 .. l0+35)
    const int4v* src = (const int4v*)tile;
    int4v* dst = (int4v*)(xq + ((size_t)b * LROWS + l0 + GUARD) * KQ);
#pragma unroll
    for (int it = 0; it < 6; ++it)
        dst[it * 256 + tid] = src[it * 256 + tid];

    if (blockIdx.x == 0) {          // zero guard rows lp 0..3
        int4v* g0 = (int4v*)(xq + (size_t)b * LROWS * KQ);
        if (tid < 192) g0[tid] = (int4v){0, 0, 0, 0};
    }
    if (blockIdx.x == gridDim.x - 1) {  // zero guard rows lp 8196..8199
        int4v* g1 = (int4v*)(xq + ((size_t)b * LROWS + L_ + GUARD) * KQ);
        if (tid < 192) g1[tid] = (int4v){0, 0, 0, 0};
    }
}

// ---- GEMM: s-outer / tap-inner, B column-slice resident in LDS ----
__global__ __launch_bounds__(256, 4) void gemm(
    const unsigned short* __restrict__ wa,   // [54][128][64] swizzled bf16
    const unsigned short* __restrict__ xq,   // [B_][LROWS][KQ] bf16
    const float*          __restrict__ bias,
    float*                __restrict__ out)
{
    __shared__ __align__(16) unsigned short ldsA[COUT * BK];  // 16 KB
    __shared__ __align__(16) unsigned short ldsB[136 * BK];   // 17,408 B

    const int l0   = blockIdx.x * 128;
    const int b    = blockIdx.y;
    const int tid  = threadIdx.x;
    const int lane = tid & 63;
    const int w    = tid >> 6;               // 0..3
    const int cobase = (w >> 1) * 64;
    const int nbase  = (w & 1) * 64;
    const int n5 = lane & 31;
    const int h  = lane >> 5;

    // B DMA lane pattern: lane j -> row (j>>3), slot (j&7)^((j>>3)&7)
    const int bj_row = lane >> 3;
    const size_t bLaneOff = (size_t)bj_row * KQ + (size_t)(((lane & 7) ^ (bj_row & 7)) << 3);

    // loop-invariant A fragment LDS byte addresses (XOR-swizzled)
    int aaddr[2][4];
#pragma unroll
    for (int fi = 0; fi < 2; ++fi)
#pragma unroll
        for (int kc = 0; kc < 4; ++kc) {
            const int ar = cobase + fi * 32 + n5;
            aaddr[fi][kc] = ar * 128 + ((((kc << 1) | h) ^ (ar & 7)) << 4);
        }

    f32x16 acc[2][2];
#pragma unroll
    for (int i = 0; i < 2; ++i)
#pragma unroll
        for (int j = 0; j < 2; ++j) acc[i][j] = (f32x16){};

    const unsigned short* xqb   = xq + (size_t)b * LROWS * KQ;
    const unsigned short* bbase = xqb + (size_t)l0 * KQ + bLaneOff;

#pragma unroll 1
    for (int s = 0; s < 6; ++s) {
        // stage B column slice: rows l0..l0+135, cols s*64..s*64+63 (17 groups)
        const unsigned short* bsrc = bbase + s * 64;
#pragma unroll
        for (int i = 0; i < 4; ++i) {
            const int g = w * 4 + i;
            __builtin_amdgcn_global_load_lds(
                (const __attribute__((address_space(1))) void*)(bsrc + (size_t)g * 8 * KQ),
                (__attribute__((address_space(3))) void*)((char*)ldsB + g * 1024),
                16, 0, 0);
        }
        if (w == 0)
            __builtin_amdgcn_global_load_lds(
                (const __attribute__((address_space(1))) void*)(bsrc + (size_t)16 * 8 * KQ),
                (__attribute__((address_space(3))) void*)((char*)ldsB + 16 * 1024),
                16, 0, 0);

#pragma unroll 1
        for (int tap = 0; tap < K_; ++tap) {
            const int c = tap * 6 + s;
            const unsigned short* agsrc = wa + (size_t)c * 8192 + (size_t)(w * 4) * 512 + lane * 8;
#pragma unroll
            for (int i = 0; i < 4; ++i)
                __builtin_amdgcn_global_load_lds(
                    (const __attribute__((address_space(1))) void*)(agsrc + i * 512),
                    (__attribute__((address_space(3))) void*)((char*)ldsA + (w * 4 + i) * 1024),
                    16, 0, 0);
            __syncthreads();   // drains vmcnt(0): A chunk (+B at s-start) resident
#pragma unroll
            for (int kc = 0; kc < 4; ++kc) {
                const int br0 = tap + nbase + n5;
                const int ba0 = br0 * 128 + ((((kc << 1) | h) ^ (br0 & 7)) << 4);
                const int ba1 = ba0 + 32 * 128;   // (br0+32)&7 == br0&7
                const bf16x8 a0 = *(const bf16x8*)((const char*)ldsA + aaddr[0][kc]);
                const bf16x8 a1 = *(const bf16x8*)((const char*)ldsA + aaddr[1][kc]);
                const bf16x8 b0 = *(const bf16x8*)((const char*)ldsB + ba0);
                const bf16x8 b1 = *(const bf16x8*)((const char*)ldsB + ba1);
                acc[0][0] = __builtin_amdgcn_mfma_f32_32x32x16_bf16(a0, b0, acc[0][0], 0, 0, 0);
                acc[0][1] = __builtin_amdgcn_mfma_f32_32x32x16_bf16(a0, b1, acc[0][1], 0, 0, 0);
                acc[1][0] = __builtin_amdgcn_mfma_f32_32x32x16_bf16(a1, b0, acc[1][0], 0, 0, 0);
                acc[1][1] = __builtin_amdgcn_mfma_f32_32x32x16_bf16(a1, b1, acc[1][1], 0, 0, 0);
            }
            __syncthreads();   // all reads done before next chunk's DMA overwrites
        }
    }

    // ---- epilogue: + bias, coalesced stores ----
#pragma unroll
    for (int fi = 0; fi < 2; ++fi)
#pragma unroll
        for (int bj = 0; bj < 2; ++bj)
#pragma unroll
            for (int r = 0; r < 16; ++r) {
                const int co = cobase + fi * 32 + (r & 3) + 8 * (r >> 2) + 4 * h;
                const int l  = l0 + nbase + bj * 32 + n5;
                out[((size_t)(b * COUT + co)) * L_ + l] = acc[fi][bj][r] + bias[co];
            }
}

extern "C" void kernel_launch(void* const* d_in, const int* in_sizes, int n_in,
                              void* d_out, int out_size, void* d_ws, size_t ws_size,
                              hipStream_t stream) {
    const float* x      = (const float*)d_in[0];  // 16*128*8192
    const float* w      = (const float*)d_in[1];  // 128*384*9
    const float* bias   = (const float*)d_in[2];  // 128
    const float* shifts = (const float*)d_in[3];  // 128*2
    float* out = (float*)d_out;

    const size_t need = (size_t)XQOFF + (size_t)B_ * LROWS * KQ * 2;  // ~101.8 MB
    if (ws_size < need) return;   // clean fail instead of OOB corruption

    unsigned short* wa = (unsigned short*)d_ws;                       // 884,736 B
    unsigned short* xq = (unsigned short*)((char*)d_ws + XQOFF);      // 100.76 MB

    const int nw = COUT * KTOT;                                       // 442,368
    prep_weights<<<(nw + 255) / 256, 256, 0, stream>>>(w, wa);

    dim3 gq(L_ / 32, B_);                                             // 256 x 16
    xq_prep<<<gq, 256, 0, stream>>>(x, shifts, xq);

    dim3 gg(L_ / 128, B_);                                            // 64 x 16 = 1024
    gemm<<<gg, 256, 0, stream>>>(wa, xq, bias, out);
}